// Round 1
// baseline (111.789 us; speedup 1.0000x reference)
//
#include <hip/hip_runtime.h>
#include <math.h>

// Problem constants (fixed by the reference).
#define B_ 256
#define J_ 10
#define I_ 1152
#define N_ 16
#define C_ 6      // i-chunks per batch element (grid.x)
#define IPC 192   // i per chunk
#define PASSES 3  // 64 i-rows per pass, 3 passes per chunk

__device__ __forceinline__ float4 ld4(const float* p) {
  return *(const float4*)p;
}

// One streaming pass over u_hat.
// MODE 0: c = 1 (plain sum over i)  -> P = partial S0
// MODE 1: c = softmax_j(u.w + mv)   -> P = partial s
// Output P[chunk][b][j][n] (partial sums over this chunk's i-range).
template <int MODE>
__global__ __launch_bounds__(256) void pass_kernel(
    const float* __restrict__ u, const float* __restrict__ w,
    const float* __restrict__ mv, float* __restrict__ P) {
  const int tid = threadIdx.x;
  const int q = tid & 3;    // n-quad (float4 of the 16 pose dims)
  const int il = tid >> 2;  // local i row 0..63
  const int chunk = blockIdx.x;
  const int b = blockIdx.y;

  float4 wq[J_];
  float mvj[J_];
  if (MODE == 1) {
#pragma unroll
    for (int j = 0; j < J_; ++j) {
      wq[j] = ld4(&w[(b * J_ + j) * N_ + q * 4]);
      mvj[j] = mv[b * J_ + j];
    }
  }

  float4 acc[J_];
#pragma unroll
  for (int j = 0; j < J_; ++j) acc[j] = make_float4(0.f, 0.f, 0.f, 0.f);

  const size_t ubase = (size_t)b * J_ * I_ * N_;
  for (int p = 0; p < PASSES; ++p) {
    const int i = chunk * IPC + p * 64 + il;
    float4 uj[J_];
#pragma unroll
    for (int j = 0; j < J_; ++j)
      uj[j] = ld4(&u[ubase + ((size_t)j * I_ + i) * N_ + q * 4]);

    if (MODE == 0) {
#pragma unroll
      for (int j = 0; j < J_; ++j) {
        acc[j].x += uj[j].x;
        acc[j].y += uj[j].y;
        acc[j].z += uj[j].z;
        acc[j].w += uj[j].w;
      }
    } else {
      float d[J_];
#pragma unroll
      for (int j = 0; j < J_; ++j) {
        float t = uj[j].x * wq[j].x + uj[j].y * wq[j].y + uj[j].z * wq[j].z +
                  uj[j].w * wq[j].w;
        // sum the 4 n-quads (lanes differing in bits 0..1) -> full 16-dot
        t += __shfl_xor(t, 1);
        t += __shfl_xor(t, 2);
        d[j] = t + mvj[j];
      }
      float m = d[0];
#pragma unroll
      for (int j = 1; j < J_; ++j) m = fmaxf(m, d[j]);
      float se = 0.f;
#pragma unroll
      for (int j = 0; j < J_; ++j) {
        d[j] = __expf(d[j] - m);
        se += d[j];
      }
      const float inv = 1.f / se;
#pragma unroll
      for (int j = 0; j < J_; ++j) {
        const float c = d[j] * inv;
        acc[j].x = fmaf(c, uj[j].x, acc[j].x);
        acc[j].y = fmaf(c, uj[j].y, acc[j].y);
        acc[j].z = fmaf(c, uj[j].z, acc[j].z);
        acc[j].w = fmaf(c, uj[j].w, acc[j].w);
      }
    }
  }

  // Reduce over i within the workgroup.
  // Step 1: butterfly over il bits inside each wave (offsets 4..32).
  __shared__ float red[J_ * 64];
  const int lane = tid & 63;
  const int wv = tid >> 6;
#pragma unroll
  for (int j = 0; j < J_; ++j) {
    float4 a = acc[j];
#pragma unroll
    for (int off = 4; off < 64; off <<= 1) {
      a.x += __shfl_xor(a.x, off);
      a.y += __shfl_xor(a.y, off);
      a.z += __shfl_xor(a.z, off);
      a.w += __shfl_xor(a.w, off);
    }
    if (lane < 4) {  // lane == q for lanes 0..3
      red[j * 64 + wv * 16 + lane * 4 + 0] = a.x;
      red[j * 64 + wv * 16 + lane * 4 + 1] = a.y;
      red[j * 64 + wv * 16 + lane * 4 + 2] = a.z;
      red[j * 64 + wv * 16 + lane * 4 + 3] = a.w;
    }
  }
  __syncthreads();
  // Step 2: sum the 4 waves, write partial.
  if (tid < J_ * N_) {
    const int j = tid >> 4, n = tid & 15;
    const float s = red[j * 64 + 0 + n] + red[j * 64 + 16 + n] +
                    red[j * 64 + 32 + n] + red[j * 64 + 48 + n];
    P[((chunk * B_ + b) * J_ + j) * N_ + n] = s;
  }
}

// v0 = squash(S0/J + bias); w = v0; mv = 0.
__global__ __launch_bounds__(192) void finishA(const float* __restrict__ P0,
                                               const float* __restrict__ bias,
                                               float* __restrict__ w,
                                               float* __restrict__ mv) {
  const int b = blockIdx.x, t = threadIdx.x;
  if (t < J_ * N_) {
    const int j = t >> 4, n = t & 15;
    float s = 0.f;
    for (int c = 0; c < C_; ++c) s += P0[((c * B_ + b) * J_ + j) * N_ + n];
    s = s * (1.f / (float)J_) + bias[j * N_ + n];
    float sq = s * s;
    sq += __shfl_xor(sq, 1);
    sq += __shfl_xor(sq, 2);
    sq += __shfl_xor(sq, 4);
    sq += __shfl_xor(sq, 8);
    const float v0 = (sq / (1.f + sq)) * s * rsqrtf(sq + 1e-8f);
    w[(b * J_ + j) * N_ + n] = v0;
    if (n == 0) mv[b * J_ + j] = 0.f;
  }
}

// v1 = squash(s1+bias); w <- v0+v1; avg_b = S0.w/I; logsumexp threshold; mv.
__global__ __launch_bounds__(192) void finishB(const float* __restrict__ P0,
                                               const float* __restrict__ P1,
                                               const float* __restrict__ bias,
                                               float* __restrict__ w,
                                               float* __restrict__ mv) {
  __shared__ float avg[J_];
  __shared__ float thr;
  const int b = blockIdx.x, t = threadIdx.x;
  const int j = t >> 4, n = t & 15;
  float w2 = 0.f;
  if (t < J_ * N_) {
    float s = bias[j * N_ + n];
    for (int c = 0; c < C_; ++c) s += P1[((c * B_ + b) * J_ + j) * N_ + n];
    float sq = s * s;
    sq += __shfl_xor(sq, 1);
    sq += __shfl_xor(sq, 2);
    sq += __shfl_xor(sq, 4);
    sq += __shfl_xor(sq, 8);
    const float v1 = (sq / (1.f + sq)) * s * rsqrtf(sq + 1e-8f);
    w2 = w[(b * J_ + j) * N_ + n] + v1;
    float S0 = 0.f;
    for (int c = 0; c < C_; ++c) S0 += P0[((c * B_ + b) * J_ + j) * N_ + n];
    float pa = S0 * w2;
    pa += __shfl_xor(pa, 1);
    pa += __shfl_xor(pa, 2);
    pa += __shfl_xor(pa, 4);
    pa += __shfl_xor(pa, 8);
    if (n == 0) avg[j] = pa * (1.f / (float)I_);
  }
  __syncthreads();
  if (t == 0) {
    float a = avg[0];
    for (int jj = 1; jj < J_; ++jj) a = fmaxf(a, avg[jj]);
    float se = 0.f;
    for (int jj = 0; jj < J_; ++jj) se += expf(avg[jj] - a);
    thr = logf(0.1f) + a + logf(se);
  }
  __syncthreads();
  if (t < J_ * N_) {
    w[(b * J_ + j) * N_ + n] = w2;
    if (n == 0) mv[b * J_ + j] = (avg[j] < thr) ? -1e30f : 0.f;
  }
}

// v2 = squash(s2+bias); out = delete ? 0 : v2.
__global__ __launch_bounds__(192) void finishC(const float* __restrict__ P2,
                                               const float* __restrict__ bias,
                                               const float* __restrict__ mv,
                                               float* __restrict__ out) {
  const int b = blockIdx.x, t = threadIdx.x;
  if (t < J_ * N_) {
    const int j = t >> 4, n = t & 15;
    float s = bias[j * N_ + n];
    for (int c = 0; c < C_; ++c) s += P2[((c * B_ + b) * J_ + j) * N_ + n];
    float sq = s * s;
    sq += __shfl_xor(sq, 1);
    sq += __shfl_xor(sq, 2);
    sq += __shfl_xor(sq, 4);
    sq += __shfl_xor(sq, 8);
    const float v2 = (sq / (1.f + sq)) * s * rsqrtf(sq + 1e-8f);
    const bool del = mv[b * J_ + j] < -1e29f;
    out[(b * J_ + j) * N_ + n] = del ? 0.f : v2;
  }
}

extern "C" void kernel_launch(void* const* d_in, const int* in_sizes, int n_in,
                              void* d_out, int out_size, void* d_ws,
                              size_t ws_size, hipStream_t stream) {
  const float* u = (const float*)d_in[0];     // [B,J,I,N]
  const float* bias = (const float*)d_in[1];  // [J,N]
  // d_in[2] = iters (always 3; structure hardcoded)
  float* ws = (float*)d_ws;
  const size_t psz = (size_t)C_ * B_ * J_ * N_;
  float* P0 = ws;          // partial S0 (kept; needed for threshold)
  float* P1 = P0 + psz;    // partial s (iter1, reused for iter2)
  float* w = P1 + psz;     // running sum of v's [B,J,N]
  float* mv = w + (size_t)B_ * J_ * N_;  // per-(b,j) additive mask
  float* out = (float*)d_out;

  dim3 gp(C_, B_);
  // iter 0: S0 = sum_i u ; v0 = squash(S0/J + bias)
  hipLaunchKernelGGL((pass_kernel<0>), gp, dim3(256), 0, stream, u, (const float*)nullptr,
                     (const float*)nullptr, P0);
  finishA<<<B_, 192, 0, stream>>>(P0, bias, w, mv);
  // iter 1: c = softmax_j(u.v0) ; v1 = squash(s1) ; sparsify mask
  hipLaunchKernelGGL((pass_kernel<1>), gp, dim3(256), 0, stream, u, w, mv, P1);
  finishB<<<B_, 192, 0, stream>>>(P0, P1, bias, w, mv);
  // iter 2: c = softmax_j(u.(v0+v1) masked) ; v = squash(s2) masked
  hipLaunchKernelGGL((pass_kernel<1>), gp, dim3(256), 0, stream, u, w, mv, P1);
  finishC<<<B_, 192, 0, stream>>>(P1, bias, mv, out);
}